// Round 6
// baseline (673.786 us; speedup 1.0000x reference)
//
#include <hip/hip_runtime.h>
#include <math.h>

#define M0 131072
#define NC 4096
#define FDIM 324   // 6*54

// -------- Kernel 1: per-atom conv pipeline + atomic segment sum ----------
// One wave (64 lanes) per atom; 4 atoms per 256-thread block.
// All conv loops are k-unrolled with a rolling 2-register (float2) window:
// 1 ds_read_b64 (immediate offset) feeding 6-36 FMAs, weights in SGPRs.
__global__ __launch_bounds__(256, 8) void atom_kernel(
    const float* __restrict__ oh_g,    // [M0,92]
    const float* __restrict__ env_g,   // [M0,55]
    const int*   __restrict__ idx_g,   // [M0] sorted
    const float* __restrict__ wA, const float* __restrict__ bA,  // [3*20],[3]
    const float* __restrict__ w1, const float* __restrict__ b1,  // [3*20],[3]
    const float* __restrict__ w2, const float* __restrict__ b2,  // [6*3*20],[6]
    float* __restrict__ sums,          // [NC,324]
    float* __restrict__ counts)        // [NC]
{
    __shared__ __align__(16) float s_total[4][280];   // concat(atom[219], env[55]) = 274
    __shared__ __align__(16) float s_one1[4][384];    // conv1 pooled [3][128]; first 92 = one-hot scratch

    // XCD-chunk swizzle: contiguous atom ranges per XCD -> same-crystal atomics
    // stay in one L2.
    const int bid = (blockIdx.x & 7) * (M0 / 4 / 8) + (blockIdx.x >> 3);

    const int wave = threadIdx.x >> 6;
    const int lane = threadIdx.x & 63;
    const int atom = bid * 4 + wave;

    float* total = s_total[wave];
    float* one1  = s_one1[wave];
    float* oh    = one1;                   // scratch alias: one-hot row [92]

    const int cry = idx_g[atom];

    // ---- Phase A: load one-hot (92 f32) and env (55 f32) ----
    if (lane < 46) {
        const float2 v = *reinterpret_cast<const float2*>(oh_g + (size_t)atom * 92 + 2 * lane);
        oh[2 * lane]     = v.x;
        oh[2 * lane + 1] = v.y;
    }
    if (lane < 55) {
        total[219 + lane] = env_g[(size_t)atom * 55 + lane];
    }
    __syncthreads();

    // ---- Phase B: conva [1,92] -> relu -> total[0..218]  (3 ch x 73 pos) ----
    // No pooling: read one f32 per k, use it 3x immediately.
    #pragma unroll
    for (int r = 0; r < 2; ++r) {
        const int p = lane + r * 64;
        if (p < 73) {
            float a0 = bA[0], a1 = bA[1], a2 = bA[2];
            #pragma unroll
            for (int k = 0; k < 20; ++k) {
                const float x = oh[p + k];             // ds_read_b32 base+4k
                a0 = fmaf(x, wA[k],      a0);
                a1 = fmaf(x, wA[20 + k], a1);
                a2 = fmaf(x, wA[40 + k], a2);
            }
            total[p]       = fmaxf(a0, 0.f);
            total[73 + p]  = fmaxf(a1, 0.f);
            total[146 + p] = fmaxf(a2, 0.f);
        }
    }
    __syncthreads();

    // ---- Phase C: conv1 (1->3, K=20) + relu + maxpool2 -> one1[3][128] ----
    // Rolling float2 window: elements [2q+k, 2q+k+1] live; 1 b64 read / 2 k-steps.
    {
        const float2* tot2 = reinterpret_cast<const float2*>(total);
        #pragma unroll
        for (int r = 0; r < 2; ++r) {
            const int q = lane + r * 64;
            if (q < 127) {
                float acc0[3], acc1[3];
                #pragma unroll
                for (int c = 0; c < 3; ++c) { acc0[c] = b1[c]; acc1[c] = acc0[c]; }
                float2 t = tot2[q];                    // elements 2q, 2q+1
                #pragma unroll
                for (int k = 0; k < 20; k += 2) {
                    const float2 nt = tot2[q + (k >> 1) + 1];  // 2q+k+2, 2q+k+3
                    #pragma unroll
                    for (int c = 0; c < 3; ++c) {
                        const float w0 = w1[c * 20 + k];
                        const float w1v = w1[c * 20 + k + 1];
                        acc0[c] = fmaf(t.x,  w0,  acc0[c]);
                        acc1[c] = fmaf(t.y,  w0,  acc1[c]);
                        acc0[c] = fmaf(t.y,  w1v, acc0[c]);
                        acc1[c] = fmaf(nt.x, w1v, acc1[c]);
                    }
                    t = nt;
                }
                #pragma unroll
                for (int c = 0; c < 3; ++c)
                    one1[c * 128 + q] = fmaxf(fmaxf(acc0[c], acc1[c]), 0.f);
            }
        }
    }
    __syncthreads();

    // ---- Phase D: conv2 (3->6, K=20) + relu + maxpool2 -> [6][54], atomic add ----
    if (lane < 54) {
        const int q = lane;
        const float2* o2 = reinterpret_cast<const float2*>(one1);  // stride 64 f2 / ch
        float acc0[6], acc1[6];
        #pragma unroll
        for (int c2 = 0; c2 < 6; ++c2) { acc0[c2] = b2[c2]; acc1[c2] = acc0[c2]; }
        float2 a = o2[q], b = o2[64 + q], c = o2[128 + q];
        #pragma unroll
        for (int k = 0; k < 20; k += 2) {
            const float2 na = o2[      q + (k >> 1) + 1];
            const float2 nb = o2[ 64 + q + (k >> 1) + 1];
            const float2 nc = o2[128 + q + (k >> 1) + 1];
            #pragma unroll
            for (int c2 = 0; c2 < 6; ++c2) {
                const float wa0 = w2[(c2 * 3 + 0) * 20 + k];
                const float wb0 = w2[(c2 * 3 + 1) * 20 + k];
                const float wc0 = w2[(c2 * 3 + 2) * 20 + k];
                acc0[c2] = fmaf(a.x, wa0, acc0[c2]);
                acc1[c2] = fmaf(a.y, wa0, acc1[c2]);
                acc0[c2] = fmaf(b.x, wb0, acc0[c2]);
                acc1[c2] = fmaf(b.y, wb0, acc1[c2]);
                acc0[c2] = fmaf(c.x, wc0, acc0[c2]);
                acc1[c2] = fmaf(c.y, wc0, acc1[c2]);
                const float wa1 = w2[(c2 * 3 + 0) * 20 + k + 1];
                const float wb1 = w2[(c2 * 3 + 1) * 20 + k + 1];
                const float wc1 = w2[(c2 * 3 + 2) * 20 + k + 1];
                acc0[c2] = fmaf(a.y,  wa1, acc0[c2]);
                acc1[c2] = fmaf(na.x, wa1, acc1[c2]);
                acc0[c2] = fmaf(b.y,  wb1, acc0[c2]);
                acc1[c2] = fmaf(nb.x, wb1, acc1[c2]);
                acc0[c2] = fmaf(c.y,  wc1, acc0[c2]);
                acc1[c2] = fmaf(nc.x, wc1, acc1[c2]);
            }
            a = na; b = nb; c = nc;
        }
        float* dst = sums + (size_t)cry * FDIM + q;
        #pragma unroll
        for (int c2 = 0; c2 < 6; ++c2)
            atomicAdd(dst + c2 * 54, fmaxf(fmaxf(acc0[c2], acc1[c2]), 0.f));
    }
    if (lane == 0) atomicAdd(&counts[cry], 1.0f);
}

// -------- Kernel 2: per-crystal mean+relu, 324->32 softplus, 32->1 ----------
__global__ __launch_bounds__(64) void head_kernel(
    const float* __restrict__ sums, const float* __restrict__ counts,
    const float* __restrict__ lin_w, const float* __restrict__ lin_b,
    const float* __restrict__ lin1_w, const float* __restrict__ lin1_b,
    float* __restrict__ out)
{
    __shared__ float p[FDIM];
    const int c = blockIdx.x;
    const int lane = threadIdx.x;
    const float inv = 1.0f / fmaxf(counts[c], 1.0f);
    for (int i = lane; i < FDIM; i += 64)
        p[i] = fmaxf(sums[(size_t)c * FDIM + i] * inv, 0.f);
    __syncthreads();

    float r = 0.f;
    if (lane < 32) {
        float acc = lin_b[lane];
        const float* wrow = lin_w + lane * FDIM;
        #pragma unroll 4
        for (int i = 0; i < FDIM; ++i) acc = fmaf(p[i], wrow[i], acc);
        // stable softplus
        const float sp = (acc > 0.f) ? acc + log1pf(expf(-acc)) : log1pf(expf(acc));
        r = sp * lin1_w[lane];
    }
    #pragma unroll
    for (int off = 16; off; off >>= 1) r += __shfl_down(r, off);
    if (lane == 0) out[c] = r + lin1_b[0];
}

extern "C" void kernel_launch(void* const* d_in, const int* in_sizes, int n_in,
                              void* d_out, int out_size, void* d_ws, size_t ws_size,
                              hipStream_t stream) {
    (void)in_sizes; (void)n_in; (void)out_size; (void)ws_size;
    const float* oh    = (const float*)d_in[0];
    const float* env   = (const float*)d_in[1];
    const int*   idx   = (const int*)  d_in[2];
    // d_in[3] = num_segments (constant 4096)
    const float* wA    = (const float*)d_in[4];
    const float* bA    = (const float*)d_in[5];
    const float* w1    = (const float*)d_in[6];
    const float* b1    = (const float*)d_in[7];
    const float* w2    = (const float*)d_in[8];
    const float* b2    = (const float*)d_in[9];
    const float* lin_w = (const float*)d_in[10];
    const float* lin_b = (const float*)d_in[11];
    const float* lin1_w= (const float*)d_in[12];
    const float* lin1_b= (const float*)d_in[13];

    float* sums   = (float*)d_ws;             // [NC*FDIM]
    float* counts = sums + (size_t)NC * FDIM; // [NC]

    hipMemsetAsync(d_ws, 0, ((size_t)NC * FDIM + NC) * sizeof(float), stream);

    atom_kernel<<<M0 / 4, 256, 0, stream>>>(oh, env, idx, wA, bA, w1, b1, w2, b2,
                                            sums, counts);
    head_kernel<<<NC, 64, 0, stream>>>(sums, counts, lin_w, lin_b, lin1_w, lin1_b,
                                       (float*)d_out);
}

// Round 7
// 327.466 us; speedup vs baseline: 2.0576x; 2.0576x over previous
//
#include <hip/hip_runtime.h>
#include <math.h>

#define M0 131072
#define NC 4096
#define FDIM 324   // 6*54

// Element j (0..21) of an 11-float2 window, compile-time index.
#define EL(W, j) (((j) & 1) ? W[(j) >> 1].y : W[(j) >> 1].x)

// Force-load 11 float2 (22 floats) from LDS into registers. The "=v" outputs
// make register residency non-negotiable; the in-block s_waitcnt makes the
// values ready before any dataflow consumer can issue.
#define DS_WIN11(w, a)                                                         \
  asm volatile("ds_read_b64 %0, %11 offset:0\n\t"                              \
               "ds_read_b64 %1, %11 offset:8\n\t"                              \
               "ds_read_b64 %2, %11 offset:16\n\t"                             \
               "ds_read_b64 %3, %11 offset:24\n\t"                             \
               "ds_read_b64 %4, %11 offset:32\n\t"                             \
               "ds_read_b64 %5, %11 offset:40\n\t"                             \
               "ds_read_b64 %6, %11 offset:48\n\t"                             \
               "ds_read_b64 %7, %11 offset:56\n\t"                             \
               "ds_read_b64 %8, %11 offset:64\n\t"                             \
               "ds_read_b64 %9, %11 offset:72\n\t"                             \
               "ds_read_b64 %10, %11 offset:80\n\t"                            \
               "s_waitcnt lgkmcnt(0)"                                          \
               : "=v"(w[0]), "=v"(w[1]), "=v"(w[2]), "=v"(w[3]), "=v"(w[4]),   \
                 "=v"(w[5]), "=v"(w[6]), "=v"(w[7]), "=v"(w[8]), "=v"(w[9]),   \
                 "=v"(w[10])                                                   \
               : "v"(a)                                                        \
               : "memory")

// -------- Kernel 1: per-atom conv pipeline + atomic segment sum ----------
// One wave per atom; 4 atoms per 256-thread block.
__global__ __launch_bounds__(256, 4) void atom_kernel(
    const float* __restrict__ oh_g,    // [M0,92]
    const float* __restrict__ env_g,   // [M0,55]
    const int*   __restrict__ idx_g,   // [M0] sorted
    const float* __restrict__ wA, const float* __restrict__ bA,  // [3*20],[3]
    const float* __restrict__ w1, const float* __restrict__ b1,  // [3*20],[3]
    const float* __restrict__ w2, const float* __restrict__ b2,  // [6*3*20],[6]
    float* __restrict__ sums,          // [NC,324]
    float* __restrict__ counts)        // [NC]
{
    __shared__ __align__(16) float s_total[4][280];   // concat(atom[219], env[55]) = 274
    __shared__ __align__(16) float s_one1[4][384];    // conv1 pooled [3][128]; first 92 = one-hot scratch

    // XCD-chunk swizzle: contiguous atom ranges per XCD.
    const int bid = (blockIdx.x & 7) * (M0 / 4 / 8) + (blockIdx.x >> 3);

    const int wave = threadIdx.x >> 6;
    const int lane = threadIdx.x & 63;
    const int atom = bid * 4 + wave;

    float* total = s_total[wave];
    float* one1  = s_one1[wave];
    float* oh    = one1;                   // scratch alias: one-hot row [92]

    const int cry = idx_g[atom];

    // ---- Phase A: load one-hot (92) and env (55) ----
    if (lane < 46) {
        const float2 v = *reinterpret_cast<const float2*>(oh_g + (size_t)atom * 92 + 2 * lane);
        oh[2 * lane]     = v.x;
        oh[2 * lane + 1] = v.y;
    }
    if (lane < 55) {
        total[219 + lane] = env_g[(size_t)atom * 55 + lane];
    }
    __syncthreads();

    // ---- Phase B: conva -> relu -> total[0..218]  (3 ch x 73 pos) ----
    #pragma unroll
    for (int r = 0; r < 2; ++r) {
        const int p = lane + r * 64;
        if (p < 73) {
            float a0 = bA[0], a1 = bA[1], a2 = bA[2];
            #pragma unroll
            for (int k = 0; k < 20; ++k) {
                const float x = oh[p + k];
                a0 = fmaf(x, wA[k],      a0);
                a1 = fmaf(x, wA[20 + k], a1);
                a2 = fmaf(x, wA[40 + k], a2);
            }
            total[p]       = fmaxf(a0, 0.f);
            total[73 + p]  = fmaxf(a1, 0.f);
            total[146 + p] = fmaxf(a2, 0.f);
        }
    }
    __syncthreads();

    const unsigned tot_b  = (unsigned)(size_t)total;
    const unsigned one1_b = (unsigned)(size_t)one1;

    // ---- Phase C: conv1 (1->3,K=20) + relu + maxpool2 -> one1[3][128] ----
    #pragma unroll
    for (int r = 0; r < 2; ++r) {
        const int q = lane + r * 64;
        if (q < 127) {
            float2 t[11];
            DS_WIN11(t, tot_b + (unsigned)q * 8u);     // floats 2q .. 2q+21
            #pragma unroll
            for (int c = 0; c < 3; ++c) {
                float e0 = b1[c], e1 = b1[c];
                #pragma unroll
                for (int k = 0; k < 20; ++k) {
                    const float w = w1[c * 20 + k];
                    e0 = fmaf(EL(t, k),     w, e0);
                    e1 = fmaf(EL(t, k + 1), w, e1);
                }
                one1[c * 128 + q] = fmaxf(fmaxf(e0, e1), 0.f);
            }
        }
    }
    __syncthreads();

    // ---- Phase D: conv2 (3->6,K=20) + relu + maxpool2 -> [6][54], atomic add ----
    if (lane < 54) {
        const int q = lane;
        float acc0[6], acc1[6];
        #pragma unroll
        for (int c2 = 0; c2 < 6; ++c2) { acc0[c2] = b2[c2]; acc1[c2] = acc0[c2]; }
        const unsigned aD = one1_b + (unsigned)q * 8u;
        #pragma unroll
        for (int ch = 0; ch < 3; ++ch) {               // input channel sections
            float2 t[11];
            DS_WIN11(t, aD + (unsigned)ch * 512u);     // floats ch*128+2q .. +21
            #pragma unroll
            for (int c2 = 0; c2 < 6; ++c2) {
                float e0 = 0.f, e1 = 0.f;
                #pragma unroll
                for (int k = 0; k < 20; ++k) {
                    const float w = w2[(c2 * 3 + ch) * 20 + k];
                    e0 = fmaf(EL(t, k),     w, e0);
                    e1 = fmaf(EL(t, k + 1), w, e1);
                }
                acc0[c2] += e0;
                acc1[c2] += e1;
            }
        }
        float* dst = sums + (size_t)cry * FDIM + q;
        #pragma unroll
        for (int c2 = 0; c2 < 6; ++c2)
            atomicAdd(dst + c2 * 54, fmaxf(fmaxf(acc0[c2], acc1[c2]), 0.f));
    }
    if (lane == 0) atomicAdd(&counts[cry], 1.0f);
}

// -------- Kernel 2: per-crystal mean+relu, 324->32 softplus, 32->1 ----------
__global__ __launch_bounds__(64) void head_kernel(
    const float* __restrict__ sums, const float* __restrict__ counts,
    const float* __restrict__ lin_w, const float* __restrict__ lin_b,
    const float* __restrict__ lin1_w, const float* __restrict__ lin1_b,
    float* __restrict__ out)
{
    __shared__ float p[FDIM];
    const int c = blockIdx.x;
    const int lane = threadIdx.x;
    const float inv = 1.0f / fmaxf(counts[c], 1.0f);
    for (int i = lane; i < FDIM; i += 64)
        p[i] = fmaxf(sums[(size_t)c * FDIM + i] * inv, 0.f);
    __syncthreads();

    float r = 0.f;
    if (lane < 32) {
        float acc = lin_b[lane];
        const float* wrow = lin_w + lane * FDIM;
        #pragma unroll 4
        for (int i = 0; i < FDIM; ++i) acc = fmaf(p[i], wrow[i], acc);
        const float sp = (acc > 0.f) ? acc + log1pf(expf(-acc)) : log1pf(expf(acc));
        r = sp * lin1_w[lane];
    }
    #pragma unroll
    for (int off = 16; off; off >>= 1) r += __shfl_down(r, off);
    if (lane == 0) out[c] = r + lin1_b[0];
}

extern "C" void kernel_launch(void* const* d_in, const int* in_sizes, int n_in,
                              void* d_out, int out_size, void* d_ws, size_t ws_size,
                              hipStream_t stream) {
    (void)in_sizes; (void)n_in; (void)out_size; (void)ws_size;
    const float* oh    = (const float*)d_in[0];
    const float* env   = (const float*)d_in[1];
    const int*   idx   = (const int*)  d_in[2];
    // d_in[3] = num_segments (constant 4096)
    const float* wA    = (const float*)d_in[4];
    const float* bA    = (const float*)d_in[5];
    const float* w1    = (const float*)d_in[6];
    const float* b1    = (const float*)d_in[7];
    const float* w2    = (const float*)d_in[8];
    const float* b2    = (const float*)d_in[9];
    const float* lin_w = (const float*)d_in[10];
    const float* lin_b = (const float*)d_in[11];
    const float* lin1_w= (const float*)d_in[12];
    const float* lin1_b= (const float*)d_in[13];

    float* sums   = (float*)d_ws;             // [NC*FDIM]
    float* counts = sums + (size_t)NC * FDIM; // [NC]

    hipMemsetAsync(d_ws, 0, ((size_t)NC * FDIM + NC) * sizeof(float), stream);

    atom_kernel<<<M0 / 4, 256, 0, stream>>>(oh, env, idx, wA, bA, w1, b1, w2, b2,
                                            sums, counts);
    head_kernel<<<NC, 64, 0, stream>>>(sums, counts, lin_w, lin_b, lin1_w, lin1_b,
                                       (float*)d_out);
}